// Round 2
// baseline (416.894 us; speedup 1.0000x reference)
//
#include <hip/hip_runtime.h>
#include <math.h>

#define BB 4
#define TT 4096
#define DDIM 2048
#define PP 256                 // DD_PAIRS
#define MM (BB*TT)             // 16384 rows
#define KKDIM 2048
#define CHUNK 32
#define NCHUNK (TT/CHUNK)      // 128

typedef __attribute__((ext_vector_type(8))) short short8;   // 8 bf16 (4 VGPRs)
typedef __attribute__((ext_vector_type(4))) float f32x4;    // MFMA C/D

__device__ __forceinline__ unsigned short f2bf(float f) {
    unsigned u = __float_as_uint(f);
    u += 0x7FFF + ((u >> 16) & 1);          // round-to-nearest-even
    return (unsigned short)(u >> 16);
}
__device__ __forceinline__ float bf2f(unsigned short h) {
    return __uint_as_float(((unsigned)h) << 16);
}

// convert 8 consecutive fp32 -> hi/lo bf16 fragments (in-register)
__device__ __forceinline__ void cvt8(const float4& va, const float4& vb,
                                     short8& hi, short8& lo) {
    float f[8] = {va.x, va.y, va.z, va.w, vb.x, vb.y, vb.z, vb.w};
    #pragma unroll
    for (int j = 0; j < 8; ++j) {
        unsigned short h = f2bf(f[j]);
        hi[j] = (short)h;
        lo[j] = (short)f2bf(f[j] - bf2f(h));
    }
}

// ===========================================================================
// K0: one-shot split of W (256x2048 fp32) into hi/lo bf16. 2 MB, ~3 us.
// ===========================================================================
__global__ __launch_bounds__(256) void prep_w_k(const float* __restrict__ W,
                                                unsigned short* __restrict__ Whi,
                                                unsigned short* __restrict__ Wlo) {
    const int i = blockIdx.x * 256 + threadIdx.x;      // 131072 threads x 4 floats
    float4 v = ((const float4*)W)[i];
    unsigned short h0 = f2bf(v.x), h1 = f2bf(v.y), h2 = f2bf(v.z), h3 = f2bf(v.w);
    unsigned short l0 = f2bf(v.x - bf2f(h0)), l1 = f2bf(v.y - bf2f(h1));
    unsigned short l2 = f2bf(v.z - bf2f(h2)), l3 = f2bf(v.w - bf2f(h3));
    uint2 hp = { (unsigned)h0 | ((unsigned)h1 << 16), (unsigned)h2 | ((unsigned)h3 << 16) };
    uint2 lp = { (unsigned)l0 | ((unsigned)l1 << 16), (unsigned)l2 | ((unsigned)l3 << 16) };
    *(uint2*)&Whi[(size_t)i * 4] = hp;
    *(uint2*)&Wlo[(size_t)i * 4] = lp;
}

// ===========================================================================
// K1: barrier-free, LDS-free MFMA GEMM + fused chunk sums + fused passthrough.
// Fragment for mfma_f32_16x16x32_bf16 is 8 consecutive k of one row for both
// A and B, so lanes load fragments DIRECTLY:
//   A: 2 float4 per row from x (fp32), split hi/lo in-register
//   B: short8 from preconverted Whi/Wlo (2 MB, L2-resident)
// Wave w owns rows [w*32, w*32+32) of the 128-row tile == one cumsum chunk.
// Blocks with n-idx 0 also stream x[:,512:2048) straight to out (copy fusion).
// XCD-bijective swizzle groups the 4 N-siblings of an M-tile on one XCD.
// ===========================================================================
__global__ __launch_bounds__(256, 2) void gemm_mfma2_k(const float* __restrict__ x,
                                                       const unsigned short* __restrict__ Whi,
                                                       const unsigned short* __restrict__ Wlo,
                                                       const float* __restrict__ bias,
                                                       float* __restrict__ delta,
                                                       float* __restrict__ csum,
                                                       float* __restrict__ out) {
    // grid = (4, 128) -> 512 blocks; 512 % 8 == 0 so swizzle is bijective
    const int hw      = blockIdx.y * 4 + blockIdx.x;
    const int logical = (hw & 7) * 64 + (hw >> 3);   // XCD k gets 64 contiguous ids
    const int nidx    = logical & 3;
    const int midx    = logical >> 2;
    const int n0      = nidx * 64;
    const int m0      = midx * 128;
    const bool docopy = (nidx == 0);

    const int tid  = threadIdx.x;
    const int w    = tid >> 6;       // wave 0..3
    const int lane = tid & 63;
    const int lm   = lane & 15;      // row-in-16-tile (A) / col (B) ; C col
    const int ko   = lane >> 4;      // k-octet 0..3 ; C row-quad

    const int rowA = m0 + w * 32 + lm;
    const float* xr0 = x + (size_t)rowA * KKDIM + ko * 8;
    const float* xr1 = xr0 + (size_t)16 * KKDIM;
    const unsigned short* wh[4];
    const unsigned short* wl[4];
    #pragma unroll
    for (int nt = 0; nt < 4; ++nt) {
        size_t off = (size_t)(n0 + nt * 16 + lm) * KKDIM + ko * 8;
        wh[nt] = Whi + off;
        wl[nt] = Wlo + off;
    }

    f32x4 acc[2][4];
    #pragma unroll
    for (int i = 0; i < 2; ++i)
        #pragma unroll
        for (int j = 0; j < 4; ++j) {
            f32x4 z = {0.f, 0.f, 0.f, 0.f};
            acc[i][j] = z;
        }

    // prime the pipeline (k0 = 0)
    float4 aC0 = *(const float4*)(xr0);
    float4 aC1 = *(const float4*)(xr0 + 4);
    float4 aC2 = *(const float4*)(xr1);
    float4 aC3 = *(const float4*)(xr1 + 4);
    short8 bhC[4], blC[4];
    #pragma unroll
    for (int nt = 0; nt < 4; ++nt) {
        bhC[nt] = *(const short8*)(wh[nt]);
        blC[nt] = *(const short8*)(wl[nt]);
    }

    for (int k0 = 0; k0 < KKDIM; k0 += 32) {
        // ---- prefetch next K-step (uniform-safe dummy on last iter) ----
        const int kn = (k0 + 32 < KKDIM) ? (k0 + 32) : k0;
        float4 aN0 = *(const float4*)(xr0 + kn);
        float4 aN1 = *(const float4*)(xr0 + kn + 4);
        float4 aN2 = *(const float4*)(xr1 + kn);
        float4 aN3 = *(const float4*)(xr1 + kn + 4);
        short8 bhN[4], blN[4];
        #pragma unroll
        for (int nt = 0; nt < 4; ++nt) {
            bhN[nt] = *(const short8*)(wh[nt] + kn);
            blN[nt] = *(const short8*)(wl[nt] + kn);
        }
        // ---- in-register split of current A ----
        short8 ah0, al0, ah1, al1;
        cvt8(aC0, aC1, ah0, al0);
        cvt8(aC2, aC3, ah1, al1);
        // ---- fused passthrough copy (cols 512..2047), n-idx 0 blocks only ----
        if (docopy && k0 >= 512) {
            float* o0 = out + (size_t)rowA * DDIM + k0 + ko * 8;
            float* o1 = o0 + (size_t)16 * DDIM;
            *(float4*)o0       = aC0;
            *(float4*)(o0 + 4) = aC1;
            *(float4*)o1       = aC2;
            *(float4*)(o1 + 4) = aC3;
        }
        // ---- MFMA: 3-product split (drop lo*lo) ----
        #pragma unroll
        for (int nt = 0; nt < 4; ++nt) {
            f32x4 c0 = acc[0][nt];
            c0 = __builtin_amdgcn_mfma_f32_16x16x32_bf16(ah0, bhC[nt], c0, 0, 0, 0);
            c0 = __builtin_amdgcn_mfma_f32_16x16x32_bf16(ah0, blC[nt], c0, 0, 0, 0);
            c0 = __builtin_amdgcn_mfma_f32_16x16x32_bf16(al0, bhC[nt], c0, 0, 0, 0);
            acc[0][nt] = c0;
            f32x4 c1 = acc[1][nt];
            c1 = __builtin_amdgcn_mfma_f32_16x16x32_bf16(ah1, bhC[nt], c1, 0, 0, 0);
            c1 = __builtin_amdgcn_mfma_f32_16x16x32_bf16(ah1, blC[nt], c1, 0, 0, 0);
            c1 = __builtin_amdgcn_mfma_f32_16x16x32_bf16(al1, bhC[nt], c1, 0, 0, 0);
            acc[1][nt] = c1;
        }
        // ---- rotate buffers ----
        aC0 = aN0; aC1 = aN1; aC2 = aN2; aC3 = aN3;
        #pragma unroll
        for (int nt = 0; nt < 4; ++nt) { bhC[nt] = bhN[nt]; blC[nt] = blN[nt]; }
    }

    // ---- epilogue: bias, store delta, fused chunk sums ----
    float bsv[4];
    #pragma unroll
    for (int nt = 0; nt < 4; ++nt) bsv[nt] = bias[n0 + nt * 16 + lm];

    float cs[4] = {0.f, 0.f, 0.f, 0.f};
    #pragma unroll
    for (int mt = 0; mt < 2; ++mt)
        #pragma unroll
        for (int nt = 0; nt < 4; ++nt)
            #pragma unroll
            for (int r = 0; r < 4; ++r) {
                float val = acc[mt][nt][r] + bsv[nt];
                int m = m0 + w * 32 + mt * 16 + ko * 4 + r;
                delta[(size_t)m * PP + n0 + nt * 16 + lm] = val;
                cs[nt] += val;
            }
    #pragma unroll
    for (int nt = 0; nt < 4; ++nt) {
        float s = cs[nt];
        s += __shfl_xor(s, 16);
        s += __shfl_xor(s, 32);
        if (lane < 16)
            csum[(size_t)(m0 / CHUNK + w) * PP + n0 + nt * 16 + lane] = s;
    }
}

// ===========================================================================
// K2: rotation, cols [0,512) only. Each block computes its own chunk-prefix
// from the raw chunk sums (same summation order as the old scan_k -> bit-
// identical numerics), then applies the rotation. Passthrough already done.
// ===========================================================================
__global__ __launch_bounds__(256) void rotate2_k(const float* __restrict__ delta,
                                                 const float* __restrict__ csum,
                                                 const float* __restrict__ x,
                                                 float* __restrict__ out) {
    const int bc = blockIdx.x;            // b*NCHUNK + c
    const int c  = bc & (NCHUNK - 1);
    const int b  = bc >> 7;
    const int p  = threadIdx.x;

    // exclusive prefix over chunks [0, c) for this (b, p) chain
    const float* cs = csum + (size_t)(b * NCHUNK) * PP + p;
    float angle = 0.f;
    int c0 = 0;
    for (; c0 + 16 <= c; c0 += 16) {
        float v[16];
        #pragma unroll
        for (int j = 0; j < 16; ++j) v[j] = cs[(size_t)(c0 + j) * PP];
        #pragma unroll
        for (int j = 0; j < 16; ++j) angle += v[j];
    }
    for (; c0 < c; ++c0) angle += cs[(size_t)c0 * PP];

    const int tbase = bc * CHUNK;
    for (int t = 0; t < CHUNK; ++t) {
        size_t row = (size_t)(tbase + t);
        angle += delta[row * PP + p];
        float s, co;
        sincosf(angle, &s, &co);
        float x1 = x[row * DDIM + p];
        float x2 = x[row * DDIM + PP + p];
        out[row * DDIM + p]      = x1 * co - x2 * s;
        out[row * DDIM + PP + p] = x2 * co + x1 * s;
    }
}

// ===========================================================================
// Fallback path kernels (ws too small) — round-2 verified fp32 pipeline.
// ===========================================================================
__global__ __launch_bounds__(256) void gemm_k(const float* __restrict__ x,
                                              const float* __restrict__ W,
                                              const float* __restrict__ bias,
                                              float* __restrict__ delta,
                                              int dstride, int doff) {
    __shared__ float As[16][68];
    __shared__ float Bs[16][68];
    const int m0  = blockIdx.x * 64;
    const int n0  = blockIdx.y * 64;
    const int tid = threadIdx.x;
    const int lr  = tid >> 2;
    const int lc  = (tid & 3) << 2;
    const int tmi = tid & 15;
    const int tni = tid >> 4;
    float acc[4][4] = {};
    for (int k0 = 0; k0 < KKDIM; k0 += 16) {
        float4 a4 = *(const float4*)(x + (size_t)(m0 + lr) * KKDIM + k0 + lc);
        float4 b4 = *(const float4*)(W + (size_t)(n0 + lr) * KKDIM + k0 + lc);
        __syncthreads();
        As[lc + 0][lr] = a4.x; As[lc + 1][lr] = a4.y;
        As[lc + 2][lr] = a4.z; As[lc + 3][lr] = a4.w;
        Bs[lc + 0][lr] = b4.x; Bs[lc + 1][lr] = b4.y;
        Bs[lc + 2][lr] = b4.z; Bs[lc + 3][lr] = b4.w;
        __syncthreads();
        #pragma unroll
        for (int kk = 0; kk < 16; ++kk) {
            float4 av = *(const float4*)&As[kk][tmi * 4];
            float4 bv = *(const float4*)&Bs[kk][tni * 4];
            float am[4] = {av.x, av.y, av.z, av.w};
            float bn[4] = {bv.x, bv.y, bv.z, bv.w};
            #pragma unroll
            for (int i = 0; i < 4; ++i)
                #pragma unroll
                for (int j = 0; j < 4; ++j)
                    acc[i][j] += am[i] * bn[j];
        }
    }
    const float4 b4 = *(const float4*)(bias + n0 + tni * 4);
    #pragma unroll
    for (int i = 0; i < 4; ++i) {
        size_t m = (size_t)(m0 + tmi * 4 + i);
        float4 o;
        o.x = acc[i][0] + b4.x; o.y = acc[i][1] + b4.y;
        o.z = acc[i][2] + b4.z; o.w = acc[i][3] + b4.w;
        *(float4*)(delta + m * dstride + doff + n0 + tni * 4) = o;
    }
}

__global__ __launch_bounds__(256) void chunksum_k(const float* __restrict__ delta,
                                                  int dstride, int doff,
                                                  float* __restrict__ csum, int cstride) {
    const int bc = blockIdx.x;
    const int b  = bc / NCHUNK;
    const int c  = bc % NCHUNK;
    const int p  = threadIdx.x;
    const int tbase = b * TT + c * CHUNK;
    float s = 0.f;
    #pragma unroll 8
    for (int t = 0; t < CHUNK; ++t)
        s += delta[(size_t)(tbase + t) * dstride + doff + p];
    csum[(size_t)bc * cstride + p] = s;
}

__global__ __launch_bounds__(256) void scan_k(float* __restrict__ csum, int cstride) {
    const int idx = blockIdx.x * 256 + threadIdx.x;  // 0..1023 = b*PP + p
    const int b = idx >> 8;
    const int p = idx & 255;
    float run = 0.f;
    for (int c0 = 0; c0 < NCHUNK; c0 += 8) {
        float v[8];
        #pragma unroll
        for (int j = 0; j < 8; ++j)
            v[j] = csum[(size_t)(b * NCHUNK + c0 + j) * cstride + p];
        #pragma unroll
        for (int j = 0; j < 8; ++j) {
            float t = v[j];
            csum[(size_t)(b * NCHUNK + c0 + j) * cstride + p] = run;
            run += t;
        }
    }
}

__global__ __launch_bounds__(256) void rotate_k(const float* __restrict__ delta,
                                                int dstride, int doff,
                                                const float* __restrict__ csum, int cstride,
                                                const float* __restrict__ x,
                                                float* __restrict__ out) {
    const int bc = blockIdx.x;
    const int p  = threadIdx.x;
    const int tbase = bc * CHUNK;
    float angle = csum[(size_t)bc * cstride + p];
    for (int t = 0; t < CHUNK; ++t) {
        size_t row = (size_t)(tbase + t);
        angle += delta[row * dstride + doff + p];
        float s, co;
        sincosf(angle, &s, &co);
        float x1 = x[row * DDIM + p];
        float x2 = x[row * DDIM + PP + p];
        out[row * DDIM + p]      = x1 * co - x2 * s;
        out[row * DDIM + PP + p] = x2 * co + x1 * s;
    }
}

__global__ __launch_bounds__(256) void copy_k(const float* __restrict__ x,
                                              float* __restrict__ out) {
    const size_t row = (size_t)blockIdx.x * 4 + (threadIdx.x >> 6);
    const int lane = threadIdx.x & 63;
    const int col = 512 + (blockIdx.y * 64 + lane) * 4;
    const size_t a = row * DDIM + col;
    *(float4*)(out + a) = *(const float4*)(x + a);
}

extern "C" void kernel_launch(void* const* d_in, const int* in_sizes, int n_in,
                              void* d_out, int out_size, void* d_ws, size_t ws_size,
                              hipStream_t stream) {
    const float* x    = (const float*)d_in[0];
    const float* W    = (const float*)d_in[1];
    const float* bias = (const float*)d_in[2];
    float* out = (float*)d_out;

    const size_t delta_elems = (size_t)MM * PP;             // 4,194,304 f32
    const size_t csum_elems  = (size_t)BB * NCHUNK * PP;    //   131,072 f32
    const size_t w_elems     = (size_t)PP * KKDIM;          //   524,288 bf16 each
    const size_t need = (delta_elems + csum_elems) * sizeof(float)
                      + 2 * w_elems * sizeof(unsigned short);

    if (ws_size >= need) {
        float* delta = (float*)d_ws;
        float* csum  = (float*)d_ws + delta_elems;
        unsigned short* Whi = (unsigned short*)(csum + csum_elems);
        unsigned short* Wlo = Whi + w_elems;
        prep_w_k<<<(PP * KKDIM / 4) / 256, 256, 0, stream>>>(W, Whi, Wlo);
        gemm_mfma2_k<<<dim3(4, MM / 128), 256, 0, stream>>>(x, Whi, Wlo, bias,
                                                            delta, csum, out);
        rotate2_k<<<BB * NCHUNK, 256, 0, stream>>>(delta, csum, x, out);
    } else {
        // fallback staging in d_out (verified round-2 path)
        float* delta = out; const int dstride = DDIM, doff = 512;
        float* csum  = out + 768; const int cstride = DDIM;
        gemm_k<<<dim3(MM / 64, PP / 64), 256, 0, stream>>>(x, W, bias, delta, dstride, doff);
        chunksum_k<<<BB * NCHUNK, 256, 0, stream>>>(delta, dstride, doff, csum, cstride);
        scan_k<<<(BB * PP) / 256, 256, 0, stream>>>(csum, cstride);
        rotate_k<<<BB * NCHUNK, 256, 0, stream>>>(delta, dstride, doff, csum, cstride, x, out);
        copy_k<<<dim3(MM / 4, 6), 256, 0, stream>>>(x, out);
    }
}

// Round 3
// 327.850 us; speedup vs baseline: 1.2716x; 1.2716x over previous
//
#include <hip/hip_runtime.h>
#include <math.h>

#define BB 4
#define TT 4096
#define DDIM 2048
#define PP 256                 // DD_PAIRS
#define MM (BB*TT)             // 16384 rows
#define KKDIM 2048
#define CHUNK 32
#define NCHUNK (TT/CHUNK)      // 128

#define BK 64
#define KSTEPS (KKDIM/BK)      // 32
#define LSTRA 72               // LDS A row stride in shorts (144 B, 16B-aligned)

typedef __attribute__((ext_vector_type(8))) short short8;   // 8 bf16 (4 VGPRs)
typedef __attribute__((ext_vector_type(4))) float f32x4;    // MFMA C/D

__device__ __forceinline__ unsigned short f2bf(float f) {
    unsigned u = __float_as_uint(f);
    u += 0x7FFF + ((u >> 16) & 1);          // round-to-nearest-even
    return (unsigned short)(u >> 16);
}
__device__ __forceinline__ float bf2f(unsigned short h) {
    return __uint_as_float(((unsigned)h) << 16);
}

// 8 consecutive fp32 -> hi/lo bf16 short8
__device__ __forceinline__ void cvt8(const float4& va, const float4& vb,
                                     short8& hi, short8& lo) {
    float f[8] = {va.x, va.y, va.z, va.w, vb.x, vb.y, vb.z, vb.w};
    #pragma unroll
    for (int j = 0; j < 8; ++j) {
        unsigned short h = f2bf(f[j]);
        hi[j] = (short)h;
        lo[j] = (short)f2bf(f[j] - bf2f(h));
    }
}

// 4 fp32 -> hi uint2 + lo uint2 (4 bf16 each)
__device__ __forceinline__ void cvt4(const float4& v, uint2& hp, uint2& lp) {
    unsigned short h0 = f2bf(v.x), h1 = f2bf(v.y), h2 = f2bf(v.z), h3 = f2bf(v.w);
    unsigned short l0 = f2bf(v.x - bf2f(h0)), l1 = f2bf(v.y - bf2f(h1));
    unsigned short l2 = f2bf(v.z - bf2f(h2)), l3 = f2bf(v.w - bf2f(h3));
    hp.x = (unsigned)h0 | ((unsigned)h1 << 16); hp.y = (unsigned)h2 | ((unsigned)h3 << 16);
    lp.x = (unsigned)l0 | ((unsigned)l1 << 16); lp.y = (unsigned)l2 | ((unsigned)l3 << 16);
}

// ===========================================================================
// K0: pack W into MFMA fragment order, hi/lo bf16.
// frag f = (k0i*16 + nb)*64 + lane ; value[j] = W[nb*16+(lane&15)][k0i*32+(lane>>4)*8+j]
// A wave's B-fragment load in the GEMM is then 64 lanes x 16 B CONTIGUOUS.
// ===========================================================================
__global__ __launch_bounds__(256) void prep_wf_k(const float* __restrict__ W,
                                                 unsigned short* __restrict__ Wfh,
                                                 unsigned short* __restrict__ Wfl) {
    const int f = blockIdx.x * 256 + threadIdx.x;   // 0..65535 fragments
    const int lane = f & 63;
    const int nb   = (f >> 6) & 15;
    const int k0i  = f >> 10;                       // 0..63
    const int row  = nb * 16 + (lane & 15);
    const int kk   = k0i * 32 + (lane >> 4) * 8;
    const float* src = W + (size_t)row * KKDIM + kk;
    float4 a = *(const float4*)src;
    float4 b = *(const float4*)(src + 4);
    short8 hi, lo;
    cvt8(a, b, hi, lo);
    *(short8*)(Wfh + (size_t)f * 8) = hi;
    *(short8*)(Wfl + (size_t)f * 8) = lo;
}

// ===========================================================================
// K1: MFMA GEMM. A: LDS-staged (coalesced fp32 loads + in-reg hi/lo split),
// double-buffered, ONE barrier per BK=64 step. B: direct coalesced fragment
// loads from Wfh/Wfl (L2-resident), prefetched one k-sub ahead. Fused chunk
// sums + fused passthrough copy (nidx==0 blocks stream x[:,512:) to out from
// the registers they already loaded). XCD-bijective block swizzle.
// ===========================================================================
__global__ __launch_bounds__(256, 2) void gemm3_k(const float* __restrict__ x,
                                                  const unsigned short* __restrict__ Wfh,
                                                  const unsigned short* __restrict__ Wfl,
                                                  const float* __restrict__ bias,
                                                  float* __restrict__ delta,
                                                  float* __restrict__ csum,
                                                  float* __restrict__ out) {
    __shared__ unsigned short Ahi[2][128 * LSTRA];   // 2 x 18 KB
    __shared__ unsigned short Alo[2][128 * LSTRA];   // 2 x 18 KB  -> 72 KB total

    // grid = (4, 128) -> 512 blocks; 512 % 8 == 0 so swizzle is bijective
    const int hw      = blockIdx.y * 4 + blockIdx.x;
    const int logical = (hw & 7) * 64 + (hw >> 3);
    const int nidx    = logical & 3;
    const int midx    = logical >> 2;
    const int n0      = nidx * 64;
    const int m0      = midx * 128;
    const bool docopy = (nidx == 0);

    const int tid  = threadIdx.x;
    const int w    = tid >> 6;       // wave 0..3
    const int lane = tid & 63;
    const int lm   = lane & 15;      // A row / B col within 16-tile ; C col
    const int ko   = lane >> 4;      // k-octet ; C row-quad

    // A staging geometry: thread covers rows {r*16 + arow}, chunk ach (4 floats)
    const int arow = tid >> 4;       // 0..15
    const int ach  = tid & 15;       // 0..15 -> floats [ach*4, ach*4+4) of BK=64

    // B fragment base (in shorts): frag = (k0i*16 + nidx*4 + nt)*64 + lane
    const size_t bfbase = ((size_t)(nidx * 4) * 64 + (size_t)lane) * 8;

    f32x4 acc[2][4];
    #pragma unroll
    for (int i = 0; i < 2; ++i)
        #pragma unroll
        for (int j = 0; j < 4; ++j) {
            f32x4 z = {0.f, 0.f, 0.f, 0.f};
            acc[i][j] = z;
        }

    // ---------- prologue: stage A(it=0) into buf0, preload B ksub0 ----------
    float4 av[8];
    #pragma unroll
    for (int r = 0; r < 8; ++r)
        av[r] = *(const float4*)(x + (size_t)(m0 + r * 16 + arow) * KKDIM + ach * 4);
    #pragma unroll
    for (int r = 0; r < 8; ++r) {
        uint2 hp, lp;
        cvt4(av[r], hp, lp);
        int idx = (r * 16 + arow) * LSTRA + ach * 4;
        *(uint2*)&Ahi[0][idx] = hp;
        *(uint2*)&Alo[0][idx] = lp;
    }
    short8 bh0[4], bl0[4], bh1[4], bl1[4];
    #pragma unroll
    for (int nt = 0; nt < 4; ++nt) {
        bh0[nt] = *(const short8*)(Wfh + bfbase + (size_t)nt * 512);
        bl0[nt] = *(const short8*)(Wfl + bfbase + (size_t)nt * 512);
    }
    __syncthreads();

    for (int it = 0; it < KSTEPS; ++it) {
        const int  cur  = it & 1, nxt = cur ^ 1;
        const bool last = (it == KSTEPS - 1);
        const int  kA   = last ? it * BK : (it + 1) * BK;   // clamp on last iter

        // ---- issue next A tile (fp32, coalesced: 4 rows x 256 B per wave-load) ----
        #pragma unroll
        for (int r = 0; r < 8; ++r)
            av[r] = *(const float4*)(x + (size_t)(m0 + r * 16 + arow) * KKDIM + kA + ach * 4);

        // ---- issue B ksub1 (k0i = 2it+1), coalesced 1 KB wave-loads ----
        #pragma unroll
        for (int nt = 0; nt < 4; ++nt) {
            size_t o = bfbase + (size_t)((2 * it + 1) * 16 + nt) * 512;
            bh1[nt] = *(const short8*)(Wfh + o);
            bl1[nt] = *(const short8*)(Wfl + o);
        }

        // ---- ksub0: ds_read frags + 24 MFMA ----
        short8 ah[2], al[2];
        #pragma unroll
        for (int mt = 0; mt < 2; ++mt) {
            int idx = (w * 32 + mt * 16 + lm) * LSTRA + ko * 8;
            ah[mt] = *(const short8*)&Ahi[cur][idx];
            al[mt] = *(const short8*)&Alo[cur][idx];
        }
        #pragma unroll
        for (int mt = 0; mt < 2; ++mt)
            #pragma unroll
            for (int nt = 0; nt < 4; ++nt) {
                f32x4 c = acc[mt][nt];
                c = __builtin_amdgcn_mfma_f32_16x16x32_bf16(ah[mt], bh0[nt], c, 0, 0, 0);
                c = __builtin_amdgcn_mfma_f32_16x16x32_bf16(ah[mt], bl0[nt], c, 0, 0, 0);
                c = __builtin_amdgcn_mfma_f32_16x16x32_bf16(al[mt], bh0[nt], c, 0, 0, 0);
                acc[mt][nt] = c;
            }

        // ---- issue B ksub0 of it+1 (k0i = 2it+2, clamp on last) ----
        const int k0iN = last ? 2 * it : 2 * it + 2;
        #pragma unroll
        for (int nt = 0; nt < 4; ++nt) {
            size_t o = bfbase + (size_t)(k0iN * 16 + nt) * 512;
            bh0[nt] = *(const short8*)(Wfh + o);
            bl0[nt] = *(const short8*)(Wfl + o);
        }

        // ---- ksub1: ds_read frags + 24 MFMA ----
        #pragma unroll
        for (int mt = 0; mt < 2; ++mt) {
            int idx = (w * 32 + mt * 16 + lm) * LSTRA + 32 + ko * 8;
            ah[mt] = *(const short8*)&Ahi[cur][idx];
            al[mt] = *(const short8*)&Alo[cur][idx];
        }
        #pragma unroll
        for (int mt = 0; mt < 2; ++mt)
            #pragma unroll
            for (int nt = 0; nt < 4; ++nt) {
                f32x4 c = acc[mt][nt];
                c = __builtin_amdgcn_mfma_f32_16x16x32_bf16(ah[mt], bh1[nt], c, 0, 0, 0);
                c = __builtin_amdgcn_mfma_f32_16x16x32_bf16(ah[mt], bl1[nt], c, 0, 0, 0);
                c = __builtin_amdgcn_mfma_f32_16x16x32_bf16(al[mt], bh1[nt], c, 0, 0, 0);
                acc[mt][nt] = c;
            }

        // ---- convert + store next A tile into the other buffer ----
        #pragma unroll
        for (int r = 0; r < 8; ++r) {
            uint2 hp, lp;
            cvt4(av[r], hp, lp);
            int idx = (r * 16 + arow) * LSTRA + ach * 4;
            *(uint2*)&Ahi[nxt][idx] = hp;
            *(uint2*)&Alo[nxt][idx] = lp;
        }
        // ---- fused passthrough copy from the registers we already hold ----
        if (docopy && !last && kA >= 512) {
            #pragma unroll
            for (int r = 0; r < 8; ++r)
                *(float4*)(out + (size_t)(m0 + r * 16 + arow) * DDIM + kA + ach * 4) = av[r];
        }
        __syncthreads();
    }

    // ---- epilogue: bias, store delta, fused chunk sums ----
    float bsv[4];
    #pragma unroll
    for (int nt = 0; nt < 4; ++nt) bsv[nt] = bias[n0 + nt * 16 + lm];

    float cs[4] = {0.f, 0.f, 0.f, 0.f};
    #pragma unroll
    for (int mt = 0; mt < 2; ++mt)
        #pragma unroll
        for (int nt = 0; nt < 4; ++nt)
            #pragma unroll
            for (int r = 0; r < 4; ++r) {
                float val = acc[mt][nt][r] + bsv[nt];
                int m = m0 + w * 32 + mt * 16 + ko * 4 + r;
                delta[(size_t)m * PP + n0 + nt * 16 + lm] = val;
                cs[nt] += val;
            }
    #pragma unroll
    for (int nt = 0; nt < 4; ++nt) {
        float s = cs[nt];
        s += __shfl_xor(s, 16);
        s += __shfl_xor(s, 32);
        if (lane < 16)
            csum[(size_t)(m0 / CHUNK + w) * PP + n0 + nt * 16 + lane] = s;
    }
}

// ===========================================================================
// K2: rotation, cols [0,512). Per-block chunk-prefix (same summation order as
// before -> identical numerics), then rotation with HARDWARE sin/cos:
// fract(angle/2pi) -> v_sin_f32 / v_cos_f32 (sin(2pi x) semantics).
// ===========================================================================
__global__ __launch_bounds__(256) void rotate2_k(const float* __restrict__ delta,
                                                 const float* __restrict__ csum,
                                                 const float* __restrict__ x,
                                                 float* __restrict__ out) {
    const int bc = blockIdx.x;            // b*NCHUNK + c
    const int c  = bc & (NCHUNK - 1);
    const int b  = bc >> 7;
    const int p  = threadIdx.x;

    // exclusive prefix over chunks [0, c) for this (b, p) chain
    const float* cs = csum + (size_t)(b * NCHUNK) * PP + p;
    float angle = 0.f;
    int c0 = 0;
    for (; c0 + 16 <= c; c0 += 16) {
        float v[16];
        #pragma unroll
        for (int j = 0; j < 16; ++j) v[j] = cs[(size_t)(c0 + j) * PP];
        #pragma unroll
        for (int j = 0; j < 16; ++j) angle += v[j];
    }
    for (; c0 < c; ++c0) angle += cs[(size_t)c0 * PP];

    const int tbase = bc * CHUNK;
    const float* dp = delta + (size_t)tbase * PP + p;
    const float* xp = x + (size_t)tbase * DDIM + p;
    float*       op = out + (size_t)tbase * DDIM + p;
    const float inv2pi = 0.15915494309189535f;

    for (int t0 = 0; t0 < CHUNK; t0 += 4) {
        float dv[4], x1v[4], x2v[4];
        #pragma unroll
        for (int j = 0; j < 4; ++j) {
            dv[j]  = dp[(size_t)(t0 + j) * PP];
            x1v[j] = xp[(size_t)(t0 + j) * DDIM];
            x2v[j] = xp[(size_t)(t0 + j) * DDIM + PP];
        }
        #pragma unroll
        for (int j = 0; j < 4; ++j) {
            angle += dv[j];
            float r  = __builtin_amdgcn_fractf(angle * inv2pi);
            float s  = __builtin_amdgcn_sinf(r);
            float co = __builtin_amdgcn_cosf(r);
            op[(size_t)(t0 + j) * DDIM]      = x1v[j] * co - x2v[j] * s;
            op[(size_t)(t0 + j) * DDIM + PP] = x2v[j] * co + x1v[j] * s;
        }
    }
}

// ===========================================================================
// Fallback path kernels (ws too small) — verified fp32 pipeline, unchanged.
// ===========================================================================
__global__ __launch_bounds__(256) void gemm_k(const float* __restrict__ x,
                                              const float* __restrict__ W,
                                              const float* __restrict__ bias,
                                              float* __restrict__ delta,
                                              int dstride, int doff) {
    __shared__ float As[16][68];
    __shared__ float Bs[16][68];
    const int m0  = blockIdx.x * 64;
    const int n0  = blockIdx.y * 64;
    const int tid = threadIdx.x;
    const int lr  = tid >> 2;
    const int lc  = (tid & 3) << 2;
    const int tmi = tid & 15;
    const int tni = tid >> 4;
    float acc[4][4] = {};
    for (int k0 = 0; k0 < KKDIM; k0 += 16) {
        float4 a4 = *(const float4*)(x + (size_t)(m0 + lr) * KKDIM + k0 + lc);
        float4 b4 = *(const float4*)(W + (size_t)(n0 + lr) * KKDIM + k0 + lc);
        __syncthreads();
        As[lc + 0][lr] = a4.x; As[lc + 1][lr] = a4.y;
        As[lc + 2][lr] = a4.z; As[lc + 3][lr] = a4.w;
        Bs[lc + 0][lr] = b4.x; Bs[lc + 1][lr] = b4.y;
        Bs[lc + 2][lr] = b4.z; Bs[lc + 3][lr] = b4.w;
        __syncthreads();
        #pragma unroll
        for (int kk = 0; kk < 16; ++kk) {
            float4 av = *(const float4*)&As[kk][tmi * 4];
            float4 bv = *(const float4*)&Bs[kk][tni * 4];
            float am[4] = {av.x, av.y, av.z, av.w};
            float bn[4] = {bv.x, bv.y, bv.z, bv.w};
            #pragma unroll
            for (int i = 0; i < 4; ++i)
                #pragma unroll
                for (int j = 0; j < 4; ++j)
                    acc[i][j] += am[i] * bn[j];
        }
    }
    const float4 b4 = *(const float4*)(bias + n0 + tni * 4);
    #pragma unroll
    for (int i = 0; i < 4; ++i) {
        size_t m = (size_t)(m0 + tmi * 4 + i);
        float4 o;
        o.x = acc[i][0] + b4.x; o.y = acc[i][1] + b4.y;
        o.z = acc[i][2] + b4.z; o.w = acc[i][3] + b4.w;
        *(float4*)(delta + m * dstride + doff + n0 + tni * 4) = o;
    }
}

__global__ __launch_bounds__(256) void chunksum_k(const float* __restrict__ delta,
                                                  int dstride, int doff,
                                                  float* __restrict__ csum, int cstride) {
    const int bc = blockIdx.x;
    const int b  = bc / NCHUNK;
    const int c  = bc % NCHUNK;
    const int p  = threadIdx.x;
    const int tbase = b * TT + c * CHUNK;
    float s = 0.f;
    #pragma unroll 8
    for (int t = 0; t < CHUNK; ++t)
        s += delta[(size_t)(tbase + t) * dstride + doff + p];
    csum[(size_t)bc * cstride + p] = s;
}

__global__ __launch_bounds__(256) void scan_k(float* __restrict__ csum, int cstride) {
    const int idx = blockIdx.x * 256 + threadIdx.x;  // 0..1023 = b*PP + p
    const int b = idx >> 8;
    const int p = idx & 255;
    float run = 0.f;
    for (int c0 = 0; c0 < NCHUNK; c0 += 8) {
        float v[8];
        #pragma unroll
        for (int j = 0; j < 8; ++j)
            v[j] = csum[(size_t)(b * NCHUNK + c0 + j) * cstride + p];
        #pragma unroll
        for (int j = 0; j < 8; ++j) {
            float t = v[j];
            csum[(size_t)(b * NCHUNK + c0 + j) * cstride + p] = run;
            run += t;
        }
    }
}

__global__ __launch_bounds__(256) void rotate_k(const float* __restrict__ delta,
                                                int dstride, int doff,
                                                const float* __restrict__ csum, int cstride,
                                                const float* __restrict__ x,
                                                float* __restrict__ out) {
    const int bc = blockIdx.x;
    const int p  = threadIdx.x;
    const int tbase = bc * CHUNK;
    float angle = csum[(size_t)bc * cstride + p];
    for (int t = 0; t < CHUNK; ++t) {
        size_t row = (size_t)(tbase + t);
        angle += delta[row * dstride + doff + p];
        float s, co;
        sincosf(angle, &s, &co);
        float x1 = x[row * DDIM + p];
        float x2 = x[row * DDIM + PP + p];
        out[row * DDIM + p]      = x1 * co - x2 * s;
        out[row * DDIM + PP + p] = x2 * co + x1 * s;
    }
}

__global__ __launch_bounds__(256) void copy_k(const float* __restrict__ x,
                                              float* __restrict__ out) {
    const size_t row = (size_t)blockIdx.x * 4 + (threadIdx.x >> 6);
    const int lane = threadIdx.x & 63;
    const int col = 512 + (blockIdx.y * 64 + lane) * 4;
    const size_t a = row * DDIM + col;
    *(float4*)(out + a) = *(const float4*)(x + a);
}

extern "C" void kernel_launch(void* const* d_in, const int* in_sizes, int n_in,
                              void* d_out, int out_size, void* d_ws, size_t ws_size,
                              hipStream_t stream) {
    const float* x    = (const float*)d_in[0];
    const float* W    = (const float*)d_in[1];
    const float* bias = (const float*)d_in[2];
    float* out = (float*)d_out;

    const size_t delta_elems = (size_t)MM * PP;             // 4,194,304 f32
    const size_t csum_elems  = (size_t)BB * NCHUNK * PP;    //   131,072 f32
    const size_t w_elems     = (size_t)PP * KKDIM;          //   524,288 bf16 each
    const size_t need = (delta_elems + csum_elems) * sizeof(float)
                      + 2 * w_elems * sizeof(unsigned short);

    if (ws_size >= need) {
        float* delta = (float*)d_ws;
        float* csum  = (float*)d_ws + delta_elems;
        unsigned short* Wfh = (unsigned short*)(csum + csum_elems);
        unsigned short* Wfl = Wfh + w_elems;
        prep_wf_k<<<256, 256, 0, stream>>>(W, Wfh, Wfl);
        gemm3_k<<<dim3(4, MM / 128), 256, 0, stream>>>(x, Wfh, Wfl, bias,
                                                       delta, csum, out);
        rotate2_k<<<BB * NCHUNK, 256, 0, stream>>>(delta, csum, x, out);
    } else {
        // fallback staging in d_out (verified fp32 path)
        float* delta = out; const int dstride = DDIM, doff = 512;
        float* csum  = out + 768; const int cstride = DDIM;
        gemm_k<<<dim3(MM / 64, PP / 64), 256, 0, stream>>>(x, W, bias, delta, dstride, doff);
        chunksum_k<<<BB * NCHUNK, 256, 0, stream>>>(delta, dstride, doff, csum, cstride);
        scan_k<<<(BB * PP) / 256, 256, 0, stream>>>(csum, cstride);
        rotate_k<<<BB * NCHUNK, 256, 0, stream>>>(delta, dstride, doff, csum, cstride, x, out);
        copy_k<<<dim3(MM / 4, 6), 256, 0, stream>>>(x, out);
    }
}

// Round 4
// 316.113 us; speedup vs baseline: 1.3188x; 1.0371x over previous
//
#include <hip/hip_runtime.h>
#include <math.h>

#define BB 4
#define TT 4096
#define DDIM 2048
#define PP 256                 // DD_PAIRS
#define MM (BB*TT)             // 16384 rows
#define KKDIM 2048
#define CHUNK 32
#define NCHUNK (TT/CHUNK)      // 128

#define BK 32
#define KSTEPS (KKDIM/BK)      // 64
#define LROW 72                // LDS row unit in shorts: 32 hi + 32 lo + 8 pad = 144 B

typedef __attribute__((ext_vector_type(8))) short short8;   // 8 bf16 (4 VGPRs)
typedef __attribute__((ext_vector_type(4))) float f32x4;    // MFMA C/D

__device__ __forceinline__ unsigned short f2bf(float f) {
    unsigned u = __float_as_uint(f);
    u += 0x7FFF + ((u >> 16) & 1);          // round-to-nearest-even
    return (unsigned short)(u >> 16);
}
__device__ __forceinline__ float bf2f(unsigned short h) {
    return __uint_as_float(((unsigned)h) << 16);
}

// 8 consecutive fp32 -> hi/lo bf16 short8
__device__ __forceinline__ void cvt8(const float4& va, const float4& vb,
                                     short8& hi, short8& lo) {
    float f[8] = {va.x, va.y, va.z, va.w, vb.x, vb.y, vb.z, vb.w};
    #pragma unroll
    for (int j = 0; j < 8; ++j) {
        unsigned short h = f2bf(f[j]);
        hi[j] = (short)h;
        lo[j] = (short)f2bf(f[j] - bf2f(h));
    }
}

// 4 fp32 -> hi uint2 + lo uint2 (4 bf16 each)
__device__ __forceinline__ void cvt4(const float4& v, uint2& hp, uint2& lp) {
    unsigned short h0 = f2bf(v.x), h1 = f2bf(v.y), h2 = f2bf(v.z), h3 = f2bf(v.w);
    unsigned short l0 = f2bf(v.x - bf2f(h0)), l1 = f2bf(v.y - bf2f(h1));
    unsigned short l2 = f2bf(v.z - bf2f(h2)), l3 = f2bf(v.w - bf2f(h3));
    hp.x = (unsigned)h0 | ((unsigned)h1 << 16); hp.y = (unsigned)h2 | ((unsigned)h3 << 16);
    lp.x = (unsigned)l0 | ((unsigned)l1 << 16); lp.y = (unsigned)l2 | ((unsigned)l3 << 16);
}

// ===========================================================================
// K0: pack W into MFMA fragment order, hi/lo bf16. (unchanged from round 3)
// frag f = (k0i*16 + nb)*64 + lane ; value[j] = W[nb*16+(lane&15)][k0i*32+(lane>>4)*8+j]
// ===========================================================================
__global__ __launch_bounds__(256) void prep_wf_k(const float* __restrict__ W,
                                                 unsigned short* __restrict__ Wfh,
                                                 unsigned short* __restrict__ Wfl) {
    const int f = blockIdx.x * 256 + threadIdx.x;   // 0..65535 fragments
    const int lane = f & 63;
    const int nb   = (f >> 6) & 15;
    const int k0i  = f >> 10;                       // 0..63
    const int row  = nb * 16 + (lane & 15);
    const int kk   = k0i * 32 + (lane >> 4) * 8;
    const float* src = W + (size_t)row * KKDIM + kk;
    float4 a = *(const float4*)src;
    float4 b = *(const float4*)(src + 4);
    short8 hi, lo;
    cvt8(a, b, hi, lo);
    *(short8*)(Wfh + (size_t)f * 8) = hi;
    *(short8*)(Wfl + (size_t)f * 8) = lo;
}

// ===========================================================================
// K1: MFMA GEMM, 8-wave blocks for 16 waves/CU (4 waves/SIMD TLP).
// Tile 128(M) x 64(N), 512 threads = 8 waves = 4(wm) x 2(wn); each wave owns
// a 32x32 output (acc 2mt x 2nt) == exactly one cumsum chunk (per-wave csum,
// same shuffle tree as round 3 -> bit-identical).
// BK=32 double-buffered LDS, hi/lo interleaved per row (144 B unit, 16B-
// aligned b128 reads, ~2-way conflicts = free), ONE barrier per K-step.
// B: direct coalesced fragment loads from Wfh/Wfl (L2), ping-pong prefetch.
// Fused chunk sums + fused passthrough copy. XCD-bijective swizzle.
// ===========================================================================
#define GSTEP(CUR, NXT, BHc, BLc, BHn, BLn, IT)                               \
{                                                                             \
    const bool last_ = ((IT) == KSTEPS - 1);                                  \
    const int  kA_   = last_ ? (IT) * BK : ((IT) + 1) * BK;                   \
    float4 av0_ = *(const float4*)(xs0 + kA_);                                \
    float4 av1_ = *(const float4*)(xs1 + kA_);                                \
    const int k0iN_ = last_ ? (IT) : (IT) + 1;                                \
    _Pragma("unroll")                                                         \
    for (int nt = 0; nt < 2; ++nt) {                                          \
        size_t o = bfbase + (size_t)(k0iN_ * 16 + nt) * 512;                  \
        BHn[nt] = *(const short8*)(Wfh + o);                                  \
        BLn[nt] = *(const short8*)(Wfl + o);                                  \
    }                                                                         \
    short8 ah_[2], al_[2];                                                    \
    _Pragma("unroll")                                                         \
    for (int mt = 0; mt < 2; ++mt) {                                          \
        int idx = (wm * 32 + mt * 16 + lm) * LROW + ko * 8;                   \
        ah_[mt] = *(const short8*)&Ast[CUR][idx];                             \
        al_[mt] = *(const short8*)&Ast[CUR][idx + 32];                        \
    }                                                                         \
    _Pragma("unroll")                                                         \
    for (int mt = 0; mt < 2; ++mt)                                            \
        _Pragma("unroll")                                                     \
        for (int nt = 0; nt < 2; ++nt) {                                      \
            f32x4 c = acc[mt][nt];                                            \
            c = __builtin_amdgcn_mfma_f32_16x16x32_bf16(ah_[mt], BHc[nt], c, 0, 0, 0); \
            c = __builtin_amdgcn_mfma_f32_16x16x32_bf16(ah_[mt], BLc[nt], c, 0, 0, 0); \
            c = __builtin_amdgcn_mfma_f32_16x16x32_bf16(al_[mt], BHc[nt], c, 0, 0, 0); \
            acc[mt][nt] = c;                                                  \
        }                                                                     \
    uint2 hp0_, lp0_, hp1_, lp1_;                                             \
    cvt4(av0_, hp0_, lp0_);                                                   \
    cvt4(av1_, hp1_, lp1_);                                                   \
    *(uint2*)&Ast[NXT][sidx0]      = hp0_;                                    \
    *(uint2*)&Ast[NXT][sidx0 + 32] = lp0_;                                    \
    *(uint2*)&Ast[NXT][sidx1]      = hp1_;                                    \
    *(uint2*)&Ast[NXT][sidx1 + 32] = lp1_;                                    \
    if (docopy && !last_ && kA_ >= 512) {                                     \
        *(float4*)(os0 + kA_) = av0_;                                         \
        *(float4*)(os1 + kA_) = av1_;                                         \
    }                                                                         \
    __syncthreads();                                                          \
}

__global__ __launch_bounds__(512, 4) void gemm4_k(const float* __restrict__ x,
                                                  const unsigned short* __restrict__ Wfh,
                                                  const unsigned short* __restrict__ Wfl,
                                                  const float* __restrict__ bias,
                                                  float* __restrict__ delta,
                                                  float* __restrict__ csum,
                                                  float* __restrict__ out) {
    __shared__ unsigned short Ast[2][128 * LROW];   // 2 x 18 KB = 36 KB

    // grid = (4, 128) -> 512 blocks; 512 % 8 == 0 so swizzle is bijective
    const int hw      = blockIdx.y * 4 + blockIdx.x;
    const int logical = (hw & 7) * 64 + (hw >> 3);
    const int nidx    = logical & 3;
    const int midx    = logical >> 2;
    const int n0      = nidx * 64;
    const int m0      = midx * 128;
    const bool docopy = (nidx == 0);

    const int tid  = threadIdx.x;
    const int w    = tid >> 6;       // wave 0..7
    const int wm   = w >> 1;         // 0..3 : M quadrant (= cumsum chunk)
    const int wn   = w & 1;          // 0..1 : N half
    const int lane = tid & 63;
    const int lm   = lane & 15;      // A row / B col within 16-tile ; C col
    const int ko   = lane >> 4;      // k-octet ; C row-quad

    // A staging geometry: thread covers rows {tid>>3, 64+(tid>>3)}, chunk tid&7
    const int arow0 = tid >> 3;      // 0..63
    const int ach   = tid & 7;       // floats [ach*4, ach*4+4) of BK=32
    const int sidx0 = arow0 * LROW + ach * 4;
    const int sidx1 = (64 + arow0) * LROW + ach * 4;
    const float* xs0 = x + (size_t)(m0 + arow0) * KKDIM + ach * 4;
    const float* xs1 = x + (size_t)(m0 + 64 + arow0) * KKDIM + ach * 4;
    float* os0 = out + (size_t)(m0 + arow0) * DDIM + ach * 4;
    float* os1 = out + (size_t)(m0 + 64 + arow0) * DDIM + ach * 4;

    // B fragment base (shorts): frag = (k0i*16 + nidx*4 + wn*2 + nt)*64 + lane
    const size_t bfbase = ((size_t)(nidx * 4 + wn * 2) * 64 + (size_t)lane) * 8;

    f32x4 acc[2][2];
    #pragma unroll
    for (int i = 0; i < 2; ++i)
        #pragma unroll
        for (int j = 0; j < 2; ++j) {
            f32x4 z = {0.f, 0.f, 0.f, 0.f};
            acc[i][j] = z;
        }

    short8 bhA[2], blA[2], bhB[2], blB[2];

    // ---------- prologue: stage A(it=0) into buf0, load B(k0i=0) ----------
    {
        float4 a0 = *(const float4*)(xs0);
        float4 a1 = *(const float4*)(xs1);
        uint2 hp, lp;
        cvt4(a0, hp, lp);
        *(uint2*)&Ast[0][sidx0]      = hp;
        *(uint2*)&Ast[0][sidx0 + 32] = lp;
        cvt4(a1, hp, lp);
        *(uint2*)&Ast[0][sidx1]      = hp;
        *(uint2*)&Ast[0][sidx1 + 32] = lp;
        #pragma unroll
        for (int nt = 0; nt < 2; ++nt) {
            size_t o = bfbase + (size_t)nt * 512;
            bhA[nt] = *(const short8*)(Wfh + o);
            blA[nt] = *(const short8*)(Wfl + o);
        }
        __syncthreads();
    }

    for (int it = 0; it < KSTEPS; it += 2) {
        GSTEP(0, 1, bhA, blA, bhB, blB, it)
        GSTEP(1, 0, bhB, blB, bhA, blA, it + 1)
    }

    // ---- epilogue: bias, store delta, per-wave chunk sums (32 rows/wave) ----
    float bsv[2];
    #pragma unroll
    for (int nt = 0; nt < 2; ++nt) bsv[nt] = bias[n0 + wn * 32 + nt * 16 + lm];

    float cs[2] = {0.f, 0.f};
    #pragma unroll
    for (int mt = 0; mt < 2; ++mt)
        #pragma unroll
        for (int nt = 0; nt < 2; ++nt)
            #pragma unroll
            for (int r = 0; r < 4; ++r) {
                float val = acc[mt][nt][r] + bsv[nt];
                int m = m0 + wm * 32 + mt * 16 + ko * 4 + r;
                delta[(size_t)m * PP + n0 + wn * 32 + nt * 16 + lm] = val;
                cs[nt] += val;
            }
    #pragma unroll
    for (int nt = 0; nt < 2; ++nt) {
        float s = cs[nt];
        s += __shfl_xor(s, 16);
        s += __shfl_xor(s, 32);
        if (lane < 16)
            csum[(size_t)(m0 / CHUNK + wm) * PP + n0 + wn * 32 + nt * 16 + lane] = s;
    }
}

// ===========================================================================
// K2: rotation, cols [0,512). 4 blocks per chunk (8 rows each) for 4x TLP.
// Each block: chunk-prefix over csum (identical order) + serial within-chunk
// pre-sum over delta rows [0, seg*8) (identical order) -> bit-identical
// angles. Hardware sin/cos (fract + v_sin/v_cos, 2pi semantics).
// ===========================================================================
__global__ __launch_bounds__(256) void rotate4_k(const float* __restrict__ delta,
                                                 const float* __restrict__ csum,
                                                 const float* __restrict__ x,
                                                 float* __restrict__ out) {
    const int blk = blockIdx.x;           // 0..2047
    const int seg = blk & 3;              // quarter within chunk
    const int bc  = blk >> 2;             // b*NCHUNK + c
    const int c   = bc & (NCHUNK - 1);
    const int b   = bc >> 7;
    const int p   = threadIdx.x;

    // exclusive prefix over chunks [0, c) for this (b, p) chain
    const float* cs = csum + (size_t)(b * NCHUNK) * PP + p;
    float angle = 0.f;
    int c0 = 0;
    for (; c0 + 16 <= c; c0 += 16) {
        float v[16];
        #pragma unroll
        for (int j = 0; j < 16; ++j) v[j] = cs[(size_t)(c0 + j) * PP];
        #pragma unroll
        for (int j = 0; j < 16; ++j) angle += v[j];
    }
    for (; c0 < c; ++c0) angle += cs[(size_t)c0 * PP];

    const int tbase = bc * CHUNK;
    const float* dp = delta + (size_t)tbase * PP + p;

    // within-chunk pre-sum over rows [0, seg*8), identical add order
    const int tpre = seg * 8;
    for (int t = 0; t < tpre; t += 8) {
        float v[8];
        #pragma unroll
        for (int j = 0; j < 8; ++j) v[j] = dp[(size_t)(t + j) * PP];
        #pragma unroll
        for (int j = 0; j < 8; ++j) angle += v[j];
    }

    const float* xp = x + (size_t)tbase * DDIM + p;
    float*       op = out + (size_t)tbase * DDIM + p;
    const float inv2pi = 0.15915494309189535f;

    for (int t0 = tpre; t0 < tpre + 8; t0 += 4) {
        float dv[4], x1v[4], x2v[4];
        #pragma unroll
        for (int j = 0; j < 4; ++j) {
            dv[j]  = dp[(size_t)(t0 + j) * PP];
            x1v[j] = xp[(size_t)(t0 + j) * DDIM];
            x2v[j] = xp[(size_t)(t0 + j) * DDIM + PP];
        }
        #pragma unroll
        for (int j = 0; j < 4; ++j) {
            angle += dv[j];
            float r  = __builtin_amdgcn_fractf(angle * inv2pi);
            float s  = __builtin_amdgcn_sinf(r);
            float co = __builtin_amdgcn_cosf(r);
            op[(size_t)(t0 + j) * DDIM]      = x1v[j] * co - x2v[j] * s;
            op[(size_t)(t0 + j) * DDIM + PP] = x2v[j] * co + x1v[j] * s;
        }
    }
}

// ===========================================================================
// Fallback path kernels (ws too small) — verified fp32 pipeline, unchanged.
// ===========================================================================
__global__ __launch_bounds__(256) void gemm_k(const float* __restrict__ x,
                                              const float* __restrict__ W,
                                              const float* __restrict__ bias,
                                              float* __restrict__ delta,
                                              int dstride, int doff) {
    __shared__ float As[16][68];
    __shared__ float Bs[16][68];
    const int m0  = blockIdx.x * 64;
    const int n0  = blockIdx.y * 64;
    const int tid = threadIdx.x;
    const int lr  = tid >> 2;
    const int lc  = (tid & 3) << 2;
    const int tmi = tid & 15;
    const int tni = tid >> 4;
    float acc[4][4] = {};
    for (int k0 = 0; k0 < KKDIM; k0 += 16) {
        float4 a4 = *(const float4*)(x + (size_t)(m0 + lr) * KKDIM + k0 + lc);
        float4 b4 = *(const float4*)(W + (size_t)(n0 + lr) * KKDIM + k0 + lc);
        __syncthreads();
        As[lc + 0][lr] = a4.x; As[lc + 1][lr] = a4.y;
        As[lc + 2][lr] = a4.z; As[lc + 3][lr] = a4.w;
        Bs[lc + 0][lr] = b4.x; Bs[lc + 1][lr] = b4.y;
        Bs[lc + 2][lr] = b4.z; Bs[lc + 3][lr] = b4.w;
        __syncthreads();
        #pragma unroll
        for (int kk = 0; kk < 16; ++kk) {
            float4 av = *(const float4*)&As[kk][tmi * 4];
            float4 bv = *(const float4*)&Bs[kk][tni * 4];
            float am[4] = {av.x, av.y, av.z, av.w};
            float bn[4] = {bv.x, bv.y, bv.z, bv.w};
            #pragma unroll
            for (int i = 0; i < 4; ++i)
                #pragma unroll
                for (int j = 0; j < 4; ++j)
                    acc[i][j] += am[i] * bn[j];
        }
    }
    const float4 b4 = *(const float4*)(bias + n0 + tni * 4);
    #pragma unroll
    for (int i = 0; i < 4; ++i) {
        size_t m = (size_t)(m0 + tmi * 4 + i);
        float4 o;
        o.x = acc[i][0] + b4.x; o.y = acc[i][1] + b4.y;
        o.z = acc[i][2] + b4.z; o.w = acc[i][3] + b4.w;
        *(float4*)(delta + m * dstride + doff + n0 + tni * 4) = o;
    }
}

__global__ __launch_bounds__(256) void chunksum_k(const float* __restrict__ delta,
                                                  int dstride, int doff,
                                                  float* __restrict__ csum, int cstride) {
    const int bc = blockIdx.x;
    const int b  = bc / NCHUNK;
    const int c  = bc % NCHUNK;
    const int p  = threadIdx.x;
    const int tbase = b * TT + c * CHUNK;
    float s = 0.f;
    #pragma unroll 8
    for (int t = 0; t < CHUNK; ++t)
        s += delta[(size_t)(tbase + t) * dstride + doff + p];
    csum[(size_t)bc * cstride + p] = s;
}

__global__ __launch_bounds__(256) void scan_k(float* __restrict__ csum, int cstride) {
    const int idx = blockIdx.x * 256 + threadIdx.x;  // 0..1023 = b*PP + p
    const int b = idx >> 8;
    const int p = idx & 255;
    float run = 0.f;
    for (int c0 = 0; c0 < NCHUNK; c0 += 8) {
        float v[8];
        #pragma unroll
        for (int j = 0; j < 8; ++j)
            v[j] = csum[(size_t)(b * NCHUNK + c0 + j) * cstride + p];
        #pragma unroll
        for (int j = 0; j < 8; ++j) {
            float t = v[j];
            csum[(size_t)(b * NCHUNK + c0 + j) * cstride + p] = run;
            run += t;
        }
    }
}

__global__ __launch_bounds__(256) void rotate_k(const float* __restrict__ delta,
                                                int dstride, int doff,
                                                const float* __restrict__ csum, int cstride,
                                                const float* __restrict__ x,
                                                float* __restrict__ out) {
    const int bc = blockIdx.x;
    const int p  = threadIdx.x;
    const int tbase = bc * CHUNK;
    float angle = csum[(size_t)bc * cstride + p];
    for (int t = 0; t < CHUNK; ++t) {
        size_t row = (size_t)(tbase + t);
        angle += delta[row * dstride + doff + p];
        float s, co;
        sincosf(angle, &s, &co);
        float x1 = x[row * DDIM + p];
        float x2 = x[row * DDIM + PP + p];
        out[row * DDIM + p]      = x1 * co - x2 * s;
        out[row * DDIM + PP + p] = x2 * co + x1 * s;
    }
}

__global__ __launch_bounds__(256) void copy_k(const float* __restrict__ x,
                                              float* __restrict__ out) {
    const size_t row = (size_t)blockIdx.x * 4 + (threadIdx.x >> 6);
    const int lane = threadIdx.x & 63;
    const int col = 512 + (blockIdx.y * 64 + lane) * 4;
    const size_t a = row * DDIM + col;
    *(float4*)(out + a) = *(const float4*)(x + a);
}

extern "C" void kernel_launch(void* const* d_in, const int* in_sizes, int n_in,
                              void* d_out, int out_size, void* d_ws, size_t ws_size,
                              hipStream_t stream) {
    const float* x    = (const float*)d_in[0];
    const float* W    = (const float*)d_in[1];
    const float* bias = (const float*)d_in[2];
    float* out = (float*)d_out;

    const size_t delta_elems = (size_t)MM * PP;             // 4,194,304 f32
    const size_t csum_elems  = (size_t)BB * NCHUNK * PP;    //   131,072 f32
    const size_t w_elems     = (size_t)PP * KKDIM;          //   524,288 bf16 each
    const size_t need = (delta_elems + csum_elems) * sizeof(float)
                      + 2 * w_elems * sizeof(unsigned short);

    if (ws_size >= need) {
        float* delta = (float*)d_ws;
        float* csum  = (float*)d_ws + delta_elems;
        unsigned short* Wfh = (unsigned short*)(csum + csum_elems);
        unsigned short* Wfl = Wfh + w_elems;
        prep_wf_k<<<256, 256, 0, stream>>>(W, Wfh, Wfl);
        gemm4_k<<<dim3(4, MM / 128), 512, 0, stream>>>(x, Wfh, Wfl, bias,
                                                       delta, csum, out);
        rotate4_k<<<BB * NCHUNK * 4, 256, 0, stream>>>(delta, csum, x, out);
    } else {
        // fallback staging in d_out (verified fp32 path)
        float* delta = out; const int dstride = DDIM, doff = 512;
        float* csum  = out + 768; const int cstride = DDIM;
        gemm_k<<<dim3(MM / 64, PP / 64), 256, 0, stream>>>(x, W, bias, delta, dstride, doff);
        chunksum_k<<<BB * NCHUNK, 256, 0, stream>>>(delta, dstride, doff, csum, cstride);
        scan_k<<<(BB * PP) / 256, 256, 0, stream>>>(csum, cstride);
        rotate_k<<<BB * NCHUNK, 256, 0, stream>>>(delta, dstride, doff, csum, cstride, x, out);
        copy_k<<<dim3(MM / 4, 6), 256, 0, stream>>>(x, out);
    }
}